// Round 3
// baseline (1759.278 us; speedup 1.0000x reference)
//
#include <hip/hip_runtime.h>

#define BB 2
#define NN 4096
#define NP 1024
#define MM 32
#define CC 35
#define CIN 32

// ---------------- FPS: one block per batch ----------------
__launch_bounds__(256)
__global__ void fps_kernel(const float* __restrict__ xyz, float* __restrict__ newxyz_out)
{
#pragma clang fp contract(off)
    const int b = blockIdx.x;
    const int t = threadIdx.x;
    const float* xb = xyz + b * NN * 3;

    float px[16], py[16], pz[16], dist[16];
#pragma unroll
    for (int k = 0; k < 16; ++k) {
        int n = t + 256 * k;
        px[k] = xb[n * 3 + 0];
        py[k] = xb[n * 3 + 1];
        pz[k] = xb[n * 3 + 2];
        dist[k] = 1e10f;
    }

    __shared__ float cen[3];
    __shared__ float redV[4];
    __shared__ int   redI[4];

    int far = 0;
    for (int s = 0; s < NP; ++s) {
        // owner of current `far` publishes centroid and writes new_xyz[s]
        int ot = far & 255, ok = far >> 8;
        if (t == ot) {
            float cx = px[ok], cy = py[ok], cz = pz[ok];
            cen[0] = cx; cen[1] = cy; cen[2] = cz;
            newxyz_out[(b * NP + s) * 3 + 0] = cx;
            newxyz_out[(b * NP + s) * 3 + 1] = cy;
            newxyz_out[(b * NP + s) * 3 + 2] = cz;
        }
        __syncthreads();
        float cx = cen[0], cy = cen[1], cz = cen[2];

        float bv = -1.0f; int bi = 0x7fffffff;
#pragma unroll
        for (int k = 0; k < 16; ++k) {
            float dx = px[k] - cx, dy = py[k] - cy, dz = pz[k] - cz;
            float d = (dx * dx + dy * dy) + dz * dz;
            float dd = fminf(dist[k], d);
            dist[k] = dd;
            if (dd > bv) { bv = dd; bi = t + 256 * k; }   // ascending n -> first max kept
        }
#pragma unroll
        for (int off = 1; off < 64; off <<= 1) {
            float ov = __shfl_xor(bv, off);
            int   oi = __shfl_xor(bi, off);
            if (ov > bv || (ov == bv && oi < bi)) { bv = ov; bi = oi; }
        }
        if ((t & 63) == 0) { redV[t >> 6] = bv; redI[t >> 6] = bi; }
        __syncthreads();
        bv = redV[0]; bi = redI[0];
#pragma unroll
        for (int w = 1; w < 4; ++w) {
            float ov = redV[w]; int oi = redI[w];
            if (ov > bv || (ov == bv && oi < bi)) { bv = ov; bi = oi; }
        }
        far = bi;   // uniform across all threads (identical FP ops)
    }
}

// ---------------- kNN: one block per (b,p) ----------------
__launch_bounds__(256)
__global__ void knn_kernel(const float* __restrict__ xyz, const float* __restrict__ newxyz,
                           int* __restrict__ knn_out)
{
#pragma clang fp contract(off)
    const int bp = blockIdx.x;
    const int b = bp >> 10;
    const int t = threadIdx.x;
    const float* xb = xyz + b * NN * 3;

    const float qx = newxyz[bp * 3 + 0];
    const float qy = newxyz[bp * 3 + 1];
    const float qz = newxyz[bp * 3 + 2];
    const float qn = (qx * qx + qy * qy) + qz * qz;

    __shared__ float dist[NN];
    __shared__ float redV[4];
    __shared__ int   redI[4];

#pragma unroll
    for (int k = 0; k < 16; ++k) {
        int n = t + 256 * k;
        float x = xb[n * 3 + 0], y = xb[n * 3 + 1], z = xb[n * 3 + 2];
        float xn = (x * x + y * y) + z * z;
        float dt = (qx * x + qy * y) + qz * z;
        dist[n] = (qn + xn) - 2.0f * dt;
    }
    __syncthreads();

    for (int r = 0; r < MM; ++r) {
        float bv = 1e30f; int bi = NN;
#pragma unroll
        for (int k = 0; k < 16; ++k) {
            int n = t + 256 * k;
            float v = dist[n];
            if (v < bv) { bv = v; bi = n; }
        }
#pragma unroll
        for (int off = 1; off < 64; off <<= 1) {
            float ov = __shfl_xor(bv, off);
            int   oi = __shfl_xor(bi, off);
            if (ov < bv || (ov == bv && oi < bi)) { bv = ov; bi = oi; }
        }
        if ((t & 63) == 0) { redV[t >> 6] = bv; redI[t >> 6] = bi; }
        __syncthreads();
        bv = redV[0]; bi = redI[0];
#pragma unroll
        for (int w = 1; w < 4; ++w) {
            float ov = redV[w]; int oi = redI[w];
            if (ov < bv || (ov == bv && oi < bi)) { bv = ov; bi = oi; }
        }
        if (t == 0) { knn_out[bp * MM + r] = bi; dist[bi] = 1e30f; }
        __syncthreads();
    }
}

// ---------------- prep: transpose MLP weights ----------------
__global__ void prep_kernel(const float* __restrict__ w1, const float* __restrict__ w2,
                            const float* __restrict__ w3,
                            float* __restrict__ w1T, float* __restrict__ w2T,
                            float* __restrict__ w3T)
{
    int t = blockIdx.x * 256 + threadIdx.x;
    int stride = gridDim.x * 256;
    for (int i = t; i < 64 * CC; i += stride) { int o = i / CC, c = i % CC; w1T[c * 64 + o] = w1[i]; }
    for (int i = t; i < 64 * 64; i += stride) { int o = i >> 6, c = i & 63; w2T[c * 64 + o] = w2[i]; }
    for (int i = t; i < 128 * 64; i += stride) { int o = i >> 6, c = i & 63; w3T[c * 128 + o] = w3[i]; }
}

// ---------------- fused gather + AFA + MLP + maxpool ----------------
__launch_bounds__(256)
__global__ void afa_mlp_kernel(const float* __restrict__ xyz, const float* __restrict__ feat,
                               const float* __restrict__ newxyz, const int* __restrict__ knn,
                               const float* __restrict__ aw1, const float* __restrict__ ab1,
                               const float* __restrict__ aw2, const float* __restrict__ ab2,
                               const float* __restrict__ aww, const float* __restrict__ abw,
                               const float* __restrict__ w1T, const float* __restrict__ b1,
                               const float* __restrict__ w2T, const float* __restrict__ b2,
                               const float* __restrict__ w3T, const float* __restrict__ b3,
                               float* __restrict__ out)
{
    const int bp = blockIdx.x;
    const int b = bp >> 10, p = bp & 1023;
    const int t = threadIdx.x;

    __shared__ float xs[CC][MM];
    __shared__ float nfs[CC][MM];
    __shared__ int   idxs[MM];
    __shared__ float h1s[64][33];
    __shared__ float h2s[64][33];
    __shared__ float pmax[128][2];

    if (t < MM) idxs[t] = knn[bp * MM + t];
    __syncthreads();

    {   // gather x = concat(gxyz, gfeat) as [C][M]
        const int m = t & 31, c0 = t >> 5;
        const int id = idxs[m];
        for (int c = c0; c < CC; c += 8) {
            float v;
            if (c < 3) v = xyz[(b * NN + id) * 3 + c] - newxyz[bp * 3 + c];
            else       v = feat[(b * CIN + (c - 3)) * NN + id];
            xs[c][m] = v;
        }
    }
    __syncthreads();

    // ---- AFA: thread (i = t>>3, jg = t&7) handles j in {jg, jg+8, jg+16, jg+24}
    const int i = t >> 3, jg = t & 7;
    float xi[CC], afa[CC];
#pragma unroll
    for (int c = 0; c < CC; ++c) { xi[c] = xs[c][i]; afa[c] = 0.0f; }

#pragma unroll
    for (int jk = 0; jk < 4; ++jk) {
        const int j = jg + 8 * jk;
        float pcol[CC];
#pragma unroll
        for (int c = 0; c < CC; ++c) {
            float v = xi[c] - xs[c][j];
            if (i == j) v = xi[c];       // xi - xj + xi*eye
            pcol[c] = v;
        }
        float h1[16];
#pragma unroll
        for (int o = 0; o < 16; ++o) {
            float acc = ab1[o];
#pragma unroll
            for (int c = 0; c < CC; ++c) acc += aw1[o * CC + c] * pcol[c];
            h1[o] = fmaxf(acc, 0.0f);
        }
        float h2[16];
#pragma unroll
        for (int o = 0; o < 16; ++o) {
            float acc = ab2[o];
#pragma unroll
            for (int c = 0; c < 16; ++c) acc += aw2[o * 16 + c] * h1[c];
            h2[o] = fmaxf(acc, 0.0f);
        }
#pragma unroll
        for (int c = 0; c < CC; ++c) {
            float acc = abw[c];
#pragma unroll
            for (int k = 0; k < 16; ++k) acc += aww[c * 16 + k] * h2[k];
            afa[c] += pcol[c] * acc;
        }
    }

    // reduce afa across the 8 lanes sharing i, write nf = x + afa
#pragma unroll
    for (int c = 0; c < CC; ++c) {
        float v = afa[c];
        v += __shfl_xor(v, 1);
        v += __shfl_xor(v, 2);
        v += __shfl_xor(v, 4);
        if (jg == 0) nfs[c][i] = xi[c] + v;
    }
    __syncthreads();

    // ---- MLP layer 1: 35 -> 64
    {
        const int o = t & 63, ib = (t >> 6) << 3;
        float acc[8];
        float bb = b1[o];
#pragma unroll
        for (int k = 0; k < 8; ++k) acc[k] = bb;
        for (int c = 0; c < CC; ++c) {
            float w = w1T[c * 64 + o];
#pragma unroll
            for (int k = 0; k < 8; ++k) acc[k] += w * nfs[c][ib + k];
        }
#pragma unroll
        for (int k = 0; k < 8; ++k) h1s[o][ib + k] = fmaxf(acc[k], 0.0f);
    }
    __syncthreads();

    // ---- MLP layer 2: 64 -> 64
    {
        const int o = t & 63, ib = (t >> 6) << 3;
        float acc[8];
        float bb = b2[o];
#pragma unroll
        for (int k = 0; k < 8; ++k) acc[k] = bb;
        for (int c = 0; c < 64; ++c) {
            float w = w2T[c * 64 + o];
#pragma unroll
            for (int k = 0; k < 8; ++k) acc[k] += w * h1s[c][ib + k];
        }
#pragma unroll
        for (int k = 0; k < 8; ++k) h2s[o][ib + k] = fmaxf(acc[k], 0.0f);
    }
    __syncthreads();

    // ---- MLP layer 3: 64 -> 128, relu, maxpool over M
    {
        const int o = t & 127, ib = (t >> 7) << 4;
        float acc[16];
        float bb = b3[o];
#pragma unroll
        for (int k = 0; k < 16; ++k) acc[k] = bb;
        for (int c = 0; c < 64; ++c) {
            float w = w3T[c * 128 + o];
#pragma unroll
            for (int k = 0; k < 16; ++k) acc[k] += w * h2s[c][ib + k];
        }
        float mx = -1e30f;
#pragma unroll
        for (int k = 0; k < 16; ++k) mx = fmaxf(mx, fmaxf(acc[k], 0.0f));
        pmax[o][t >> 7] = mx;
    }
    __syncthreads();

    if (t < 128) {
        float v = fmaxf(pmax[t][0], pmax[t][1]);
        out[(b * 128 + t) * NP + p] = v;
    }
}

extern "C" void kernel_launch(void* const* d_in, const int* in_sizes, int n_in,
                              void* d_out, int out_size, void* d_ws, size_t ws_size,
                              hipStream_t stream)
{
    const float* xyz  = (const float*)d_in[0];
    const float* feat = (const float*)d_in[1];
    const float* aw1  = (const float*)d_in[2];
    const float* ab1  = (const float*)d_in[3];
    const float* aw2  = (const float*)d_in[4];
    const float* ab2  = (const float*)d_in[5];
    const float* aww  = (const float*)d_in[6];
    const float* abw  = (const float*)d_in[7];
    const float* mw1  = (const float*)d_in[8];
    const float* mb1  = (const float*)d_in[9];
    const float* mw2  = (const float*)d_in[10];
    const float* mb2  = (const float*)d_in[11];
    const float* mw3  = (const float*)d_in[12];
    const float* mb3  = (const float*)d_in[13];

    float* out    = (float*)d_out;
    float* newxyz = out;                  // (B, NP, 3) = 6144 floats
    float* out2   = out + BB * NP * 3;    // (B, 128, NP)

    int*   knn = (int*)d_ws;                                   // 2048*32 ints
    float* w1T = (float*)((char*)d_ws + (1 << 19));            // 35x64
    float* w2T = w1T + CC * 64;                                // 64x64
    float* w3T = w2T + 64 * 64;                                // 64x128

    fps_kernel<<<dim3(BB), dim3(256), 0, stream>>>(xyz, newxyz);
    prep_kernel<<<dim3(8), dim3(256), 0, stream>>>(mw1, mw2, mw3, w1T, w2T, w3T);
    knn_kernel<<<dim3(BB * NP), dim3(256), 0, stream>>>(xyz, newxyz, knn);
    afa_mlp_kernel<<<dim3(BB * NP), dim3(256), 0, stream>>>(
        xyz, feat, newxyz, knn,
        aw1, ab1, aw2, ab2, aww, abw,
        w1T, mb1, w2T, mb2, w3T, mb3, out2);
}

// Round 4
// 1128.643 us; speedup vs baseline: 1.5588x; 1.5588x over previous
//
#include <hip/hip_runtime.h>

#define BB 2
#define NN 4096
#define NP 1024
#define MM 32
#define CC 35
#define CIN 32

// ---------------- FPS: one block per batch, 4 waves ----------------
// Per-step critical path minimized: single __syncthreads per step
// (double-buffered reduce slots), centroid lookup from an LDS float4
// table (no publish round-trip), and the 64-lane argmax butterfly done
// with VALU-latency DPP for offsets 1/2/4/8 (quad_perm / mirrors are
// valid because lanes converge to identical (val,idx) before each
// mirror round; max+min-index is associative/commutative) and shfl
// only for offsets 16/32. (dist,idx) packed into one u64 key:
// dist >= 0 finite => float bits monotonic; low word = ~index so the
// u64 max picks the smallest index on ties (matches jnp.argmax).
#define DPP_XOR(CTRL) do { \
    int lo_ = (int)(unsigned)key, hi_ = (int)(unsigned)(key >> 32); \
    int olo_ = __builtin_amdgcn_mov_dpp(lo_, CTRL, 0xF, 0xF, true); \
    int ohi_ = __builtin_amdgcn_mov_dpp(hi_, CTRL, 0xF, 0xF, true); \
    unsigned long long ok_ = ((unsigned long long)(unsigned)ohi_ << 32) | (unsigned)olo_; \
    if (ok_ > key) key = ok_; \
} while (0)

__launch_bounds__(256)
__global__ void fps_kernel(const float* __restrict__ xyz, float* __restrict__ newxyz_out)
{
#pragma clang fp contract(off)
    const int b = blockIdx.x;
    const int t = threadIdx.x;
    const float* xb = xyz + b * NN * 3;

    __shared__ float4 pc[NN];                       // coord table for far-lookup
    __shared__ unsigned long long red[2][4];        // double-buffered per-wave winners

    float px[16], py[16], pz[16], dist[16];
#pragma unroll
    for (int k = 0; k < 16; ++k) {
        int n = t + 256 * k;
        float x = xb[n * 3 + 0];
        float y = xb[n * 3 + 1];
        float z = xb[n * 3 + 2];
        px[k] = x; py[k] = y; pz[k] = z;
        dist[k] = 1e10f;
        pc[n] = make_float4(x, y, z, 0.0f);
    }
    __syncthreads();

    int far = 0;
    for (int s = 0; s < NP; ++s) {
        // centroid = coords of current far (uniform index, LDS broadcast)
        float4 c = pc[far];
        if (t == 0) {
            newxyz_out[(b * NP + s) * 3 + 0] = c.x;
            newxyz_out[(b * NP + s) * 3 + 1] = c.y;
            newxyz_out[(b * NP + s) * 3 + 2] = c.z;
        }
        const float cx = c.x, cy = c.y, cz = c.z;

        // update dists, local argmax (first-index via ascending k and strict >)
        float bv = -1.0f; int bi = 0;
#pragma unroll
        for (int k = 0; k < 16; ++k) {
            float dx = px[k] - cx, dy = py[k] - cy, dz = pz[k] - cz;
            float d = (dx * dx + dy * dy) + dz * dz;
            float dd = fminf(dist[k], d);
            dist[k] = dd;
            if (dd > bv) { bv = dd; bi = t + 256 * k; }
        }

        // pack: max key == max dist, ties -> smallest index
        unsigned long long key =
            ((unsigned long long)(unsigned)__float_as_int(bv) << 32)
            | (unsigned)(0xFFFFFFFFu - (unsigned)bi);

        DPP_XOR(0xB1);   // xor 1 (quad_perm [1,0,3,2])
        DPP_XOR(0x4E);   // xor 2 (quad_perm [2,3,0,1])
        DPP_XOR(0x141);  // xor 4 (row_half_mirror; quads already converged)
        DPP_XOR(0x140);  // xor 8 (row_mirror; 8-groups already converged)
        {
            unsigned long long o = __shfl_xor(key, 16);
            if (o > key) key = o;
            o = __shfl_xor(key, 32);
            if (o > key) key = o;
        }

        const int buf = s & 1;
        if ((t & 63) == 0) red[buf][t >> 6] = key;
        __syncthreads();
        unsigned long long k0 = red[buf][0];
        unsigned long long k1 = red[buf][1];
        unsigned long long k2 = red[buf][2];
        unsigned long long k3 = red[buf][3];
        if (k1 > k0) k0 = k1;
        if (k2 > k0) k0 = k2;
        if (k3 > k0) k0 = k3;
        far = (int)(0xFFFFFFFFu - (unsigned)k0);   // uniform across all threads
    }
}

// ---------------- kNN: one block per (b,p) ----------------
__launch_bounds__(256)
__global__ void knn_kernel(const float* __restrict__ xyz, const float* __restrict__ newxyz,
                           int* __restrict__ knn_out)
{
#pragma clang fp contract(off)
    const int bp = blockIdx.x;
    const int b = bp >> 10;
    const int t = threadIdx.x;
    const float* xb = xyz + b * NN * 3;

    const float qx = newxyz[bp * 3 + 0];
    const float qy = newxyz[bp * 3 + 1];
    const float qz = newxyz[bp * 3 + 2];
    const float qn = (qx * qx + qy * qy) + qz * qz;

    __shared__ float dist[NN];
    __shared__ float redV[4];
    __shared__ int   redI[4];

#pragma unroll
    for (int k = 0; k < 16; ++k) {
        int n = t + 256 * k;
        float x = xb[n * 3 + 0], y = xb[n * 3 + 1], z = xb[n * 3 + 2];
        float xn = (x * x + y * y) + z * z;
        float dt = (qx * x + qy * y) + qz * z;
        dist[n] = (qn + xn) - 2.0f * dt;
    }
    __syncthreads();

    for (int r = 0; r < MM; ++r) {
        float bv = 1e30f; int bi = NN;
#pragma unroll
        for (int k = 0; k < 16; ++k) {
            int n = t + 256 * k;
            float v = dist[n];
            if (v < bv) { bv = v; bi = n; }
        }
#pragma unroll
        for (int off = 1; off < 64; off <<= 1) {
            float ov = __shfl_xor(bv, off);
            int   oi = __shfl_xor(bi, off);
            if (ov < bv || (ov == bv && oi < bi)) { bv = ov; bi = oi; }
        }
        if ((t & 63) == 0) { redV[t >> 6] = bv; redI[t >> 6] = bi; }
        __syncthreads();
        bv = redV[0]; bi = redI[0];
#pragma unroll
        for (int w = 1; w < 4; ++w) {
            float ov = redV[w]; int oi = redI[w];
            if (ov < bv || (ov == bv && oi < bi)) { bv = ov; bi = oi; }
        }
        if (t == 0) { knn_out[bp * MM + r] = bi; dist[bi] = 1e30f; }
        __syncthreads();
    }
}

// ---------------- prep: transpose MLP weights ----------------
__global__ void prep_kernel(const float* __restrict__ w1, const float* __restrict__ w2,
                            const float* __restrict__ w3,
                            float* __restrict__ w1T, float* __restrict__ w2T,
                            float* __restrict__ w3T)
{
    int t = blockIdx.x * 256 + threadIdx.x;
    int stride = gridDim.x * 256;
    for (int i = t; i < 64 * CC; i += stride) { int o = i / CC, c = i % CC; w1T[c * 64 + o] = w1[i]; }
    for (int i = t; i < 64 * 64; i += stride) { int o = i >> 6, c = i & 63; w2T[c * 64 + o] = w2[i]; }
    for (int i = t; i < 128 * 64; i += stride) { int o = i >> 6, c = i & 63; w3T[c * 128 + o] = w3[i]; }
}

// ---------------- fused gather + AFA + MLP + maxpool ----------------
__launch_bounds__(256)
__global__ void afa_mlp_kernel(const float* __restrict__ xyz, const float* __restrict__ feat,
                               const float* __restrict__ newxyz, const int* __restrict__ knn,
                               const float* __restrict__ aw1, const float* __restrict__ ab1,
                               const float* __restrict__ aw2, const float* __restrict__ ab2,
                               const float* __restrict__ aww, const float* __restrict__ abw,
                               const float* __restrict__ w1T, const float* __restrict__ b1,
                               const float* __restrict__ w2T, const float* __restrict__ b2,
                               const float* __restrict__ w3T, const float* __restrict__ b3,
                               float* __restrict__ out)
{
    const int bp = blockIdx.x;
    const int b = bp >> 10, p = bp & 1023;
    const int t = threadIdx.x;

    __shared__ float xs[CC][MM];
    __shared__ float nfs[CC][MM];
    __shared__ int   idxs[MM];
    __shared__ float h1s[64][33];
    __shared__ float h2s[64][33];
    __shared__ float pmax[128][2];

    if (t < MM) idxs[t] = knn[bp * MM + t];
    __syncthreads();

    {   // gather x = concat(gxyz, gfeat) as [C][M]
        const int m = t & 31, c0 = t >> 5;
        const int id = idxs[m];
        for (int c = c0; c < CC; c += 8) {
            float v;
            if (c < 3) v = xyz[(b * NN + id) * 3 + c] - newxyz[bp * 3 + c];
            else       v = feat[(b * CIN + (c - 3)) * NN + id];
            xs[c][m] = v;
        }
    }
    __syncthreads();

    // ---- AFA: thread (i = t>>3, jg = t&7) handles j in {jg, jg+8, jg+16, jg+24}
    const int i = t >> 3, jg = t & 7;
    float xi[CC], afa[CC];
#pragma unroll
    for (int c = 0; c < CC; ++c) { xi[c] = xs[c][i]; afa[c] = 0.0f; }

#pragma unroll
    for (int jk = 0; jk < 4; ++jk) {
        const int j = jg + 8 * jk;
        float pcol[CC];
#pragma unroll
        for (int c = 0; c < CC; ++c) {
            float v = xi[c] - xs[c][j];
            if (i == j) v = xi[c];       // xi - xj + xi*eye
            pcol[c] = v;
        }
        float h1[16];
#pragma unroll
        for (int o = 0; o < 16; ++o) {
            float acc = ab1[o];
#pragma unroll
            for (int c = 0; c < CC; ++c) acc += aw1[o * CC + c] * pcol[c];
            h1[o] = fmaxf(acc, 0.0f);
        }
        float h2[16];
#pragma unroll
        for (int o = 0; o < 16; ++o) {
            float acc = ab2[o];
#pragma unroll
            for (int c = 0; c < 16; ++c) acc += aw2[o * 16 + c] * h1[c];
            h2[o] = fmaxf(acc, 0.0f);
        }
#pragma unroll
        for (int c = 0; c < CC; ++c) {
            float acc = abw[c];
#pragma unroll
            for (int k = 0; k < 16; ++k) acc += aww[c * 16 + k] * h2[k];
            afa[c] += pcol[c] * acc;
        }
    }

    // reduce afa across the 8 lanes sharing i, write nf = x + afa
#pragma unroll
    for (int c = 0; c < CC; ++c) {
        float v = afa[c];
        v += __shfl_xor(v, 1);
        v += __shfl_xor(v, 2);
        v += __shfl_xor(v, 4);
        if (jg == 0) nfs[c][i] = xi[c] + v;
    }
    __syncthreads();

    // ---- MLP layer 1: 35 -> 64
    {
        const int o = t & 63, ib = (t >> 6) << 3;
        float acc[8];
        float bb = b1[o];
#pragma unroll
        for (int k = 0; k < 8; ++k) acc[k] = bb;
        for (int c = 0; c < CC; ++c) {
            float w = w1T[c * 64 + o];
#pragma unroll
            for (int k = 0; k < 8; ++k) acc[k] += w * nfs[c][ib + k];
        }
#pragma unroll
        for (int k = 0; k < 8; ++k) h1s[o][ib + k] = fmaxf(acc[k], 0.0f);
    }
    __syncthreads();

    // ---- MLP layer 2: 64 -> 64
    {
        const int o = t & 63, ib = (t >> 6) << 3;
        float acc[8];
        float bb = b2[o];
#pragma unroll
        for (int k = 0; k < 8; ++k) acc[k] = bb;
        for (int c = 0; c < 64; ++c) {
            float w = w2T[c * 64 + o];
#pragma unroll
            for (int k = 0; k < 8; ++k) acc[k] += w * h1s[c][ib + k];
        }
#pragma unroll
        for (int k = 0; k < 8; ++k) h2s[o][ib + k] = fmaxf(acc[k], 0.0f);
    }
    __syncthreads();

    // ---- MLP layer 3: 64 -> 128, relu, maxpool over M
    {
        const int o = t & 127, ib = (t >> 7) << 4;
        float acc[16];
        float bb = b3[o];
#pragma unroll
        for (int k = 0; k < 16; ++k) acc[k] = bb;
        for (int c = 0; c < 64; ++c) {
            float w = w3T[c * 128 + o];
#pragma unroll
            for (int k = 0; k < 16; ++k) acc[k] += w * h2s[c][ib + k];
        }
        float mx = -1e30f;
#pragma unroll
        for (int k = 0; k < 16; ++k) mx = fmaxf(mx, fmaxf(acc[k], 0.0f));
        pmax[o][t >> 7] = mx;
    }
    __syncthreads();

    if (t < 128) {
        float v = fmaxf(pmax[t][0], pmax[t][1]);
        out[(b * 128 + t) * NP + p] = v;
    }
}

extern "C" void kernel_launch(void* const* d_in, const int* in_sizes, int n_in,
                              void* d_out, int out_size, void* d_ws, size_t ws_size,
                              hipStream_t stream)
{
    const float* xyz  = (const float*)d_in[0];
    const float* feat = (const float*)d_in[1];
    const float* aw1  = (const float*)d_in[2];
    const float* ab1  = (const float*)d_in[3];
    const float* aw2  = (const float*)d_in[4];
    const float* ab2  = (const float*)d_in[5];
    const float* aww  = (const float*)d_in[6];
    const float* abw  = (const float*)d_in[7];
    const float* mw1  = (const float*)d_in[8];
    const float* mb1  = (const float*)d_in[9];
    const float* mw2  = (const float*)d_in[10];
    const float* mb2  = (const float*)d_in[11];
    const float* mw3  = (const float*)d_in[12];
    const float* mb3  = (const float*)d_in[13];

    float* out    = (float*)d_out;
    float* newxyz = out;                  // (B, NP, 3) = 6144 floats
    float* out2   = out + BB * NP * 3;    // (B, 128, NP)

    int*   knn = (int*)d_ws;                                   // 2048*32 ints
    float* w1T = (float*)((char*)d_ws + (1 << 19));            // 35x64
    float* w2T = w1T + CC * 64;                                // 64x64
    float* w3T = w2T + 64 * 64;                                // 64x128

    fps_kernel<<<dim3(BB), dim3(256), 0, stream>>>(xyz, newxyz);
    prep_kernel<<<dim3(8), dim3(256), 0, stream>>>(mw1, mw2, mw3, w1T, w2T, w3T);
    knn_kernel<<<dim3(BB * NP), dim3(256), 0, stream>>>(xyz, newxyz, knn);
    afa_mlp_kernel<<<dim3(BB * NP), dim3(256), 0, stream>>>(
        xyz, feat, newxyz, knn,
        aw1, ab1, aw2, ab2, aww, abw,
        w1T, mb1, w2T, mb2, w3T, mb3, out2);
}